// Round 1
// baseline (507.949 us; speedup 1.0000x reference)
//
#include <hip/hip_runtime.h>
#include <math.h>

#define N_P 256
#define T_T 1024
#define P_AR 4
#define TP (T_T - P_AR)          // 1020
#define ALPHA_LD (T_T + P_AR)    // 1028
#define NPAIRS (N_P * (N_P - 1) / 2)  // 32640
#define MCHUNK 4
#define AR_BLOCKS 256
#define BTL_BLOCKS 2040
#define PAIRS_PER_BLK (NPAIRS / BTL_BLOCKS)  // 16, exact

typedef float f4 __attribute__((ext_vector_type(4)));

// --- block reduction: 256 threads = 4 waves of 64 ---
__device__ __forceinline__ float block_reduce_sum(float v, float* tmp) {
#pragma unroll
    for (int o = 32; o > 0; o >>= 1) v += __shfl_down(v, o, 64);
    int lane = threadIdx.x & 63;
    int w    = threadIdx.x >> 6;
    if (lane == 0) tmp[w] = v;
    __syncthreads();
    if (threadIdx.x == 0) v = tmp[0] + tmp[1] + tmp[2] + tmp[3];
    return v;
}

__device__ __forceinline__ float btl_term(float z, float w, float a, float b) {
    float m   = fmaxf(a, b);
    float lse = m + __logf(1.f + __expf(-fabsf(a - b)));
    return z * (a - lse) + w * (b - lse);
}

// Fused kernel: blocks [0,256) do the AR-error path, blocks [256, 2296) do the
// log-BTL pair streaming. LDS = 4KB phi_s + 16KB a_s = 20480 B exactly ->
// 8 blocks/CU (was 36KB -> 4 blocks/CU). tmp for the reduction reuses a_s.
__global__ __launch_bounds__(256, 8) void fused_kernel(const float* __restrict__ Z,
                                                       const float* __restrict__ W,
                                                       const float* __restrict__ Phi,
                                                       const float* __restrict__ alpha,
                                                       float* __restrict__ out) {
    __shared__ float phi_s[4 * N_P];                    // 4 KB
    __shared__ __align__(16) float a_s[MCHUNK * 1024];  // 16 KB
    float* tmp = a_s;  // a_s is dead (AR) or unused (BTL) by reduction time

    const int tid = threadIdx.x;

    if (blockIdx.x < AR_BLOCKS) {
        // ---------------- AR path: block n computes summed[n, :] ----------------
        const int n = blockIdx.x;

        for (int x = tid; x < 4 * N_P; x += 256)
            phi_s[x] = Phi[(x >> 8) * (N_P * N_P) + n * N_P + (x & 255)];

        float acc0 = 0.f, acc1 = 0.f, acc2 = 0.f, acc3 = 0.f;   // summed[n, t0..t0+3]
        float cs0 = 0.f, cs1 = 0.f, cs2 = 0.f, cs3 = 0.f;       // colsum[t0..t0+3]
        float sq  = 0.f;                                         // sum(actual^2)
        const int t0 = tid * 4;      // tid 255 masked (t0 >= TP)

        for (int mc = 0; mc < N_P; mc += MCHUNK) {
            __syncthreads();   // phi_s ready (first iter) / a_s reusable
            for (int x = tid; x < MCHUNK * 256; x += 256) {
                int r = x >> 8, c = x & 255;
                ((f4*)a_s)[r * 256 + c] =
                    *(const f4*)(alpha + (size_t)(mc + r) * ALPHA_LD + c * 4);
            }
            __syncthreads();
            if (t0 < TP) {
#pragma unroll
                for (int r = 0; r < MCHUNK; ++r) {
                    const f4 av0 = ((const f4*)(a_s + r * 1024))[tid];
                    const f4 av1 = ((const f4*)(a_s + r * 1024))[tid + 1];
                    int m = mc + r;
                    float p0 = phi_s[m];
                    float p1 = phi_s[256 + m];
                    float p2 = phi_s[512 + m];
                    float p3 = phi_s[768 + m];
                    acc0 += p0 * av0.x + p1 * av0.y + p2 * av0.z + p3 * av0.w;
                    acc1 += p0 * av0.y + p1 * av0.z + p2 * av0.w + p3 * av1.x;
                    acc2 += p0 * av0.z + p1 * av0.w + p2 * av1.x + p3 * av1.y;
                    acc3 += p0 * av0.w + p1 * av1.x + p2 * av1.y + p3 * av1.z;
                    // av1 == actual[m, t0..t0+3] — column sums + squares for free
                    cs0 += av1.x; cs1 += av1.y; cs2 += av1.z; cs3 += av1.w;
                    sq  += av1.x * av1.x + av1.y * av1.y + av1.z * av1.z + av1.w * av1.w;
                }
            }
        }

        float local = 0.f;
        if (t0 < TP) {
            local = 256.f * (acc0 * acc0 + acc1 * acc1 + acc2 * acc2 + acc3 * acc3)
                  - 2.f * (acc0 * cs0 + acc1 * cs1 + acc2 * cs2 + acc3 * cs3);
            if (n == 0) local += 256.f * sq;   // N * sum(actual^2), added once
        }
        __syncthreads();   // a_s consumers done before tmp (=a_s) is overwritten
        float tot = block_reduce_sum(local, tmp);
        if (tid == 0) atomicAdd(out + 1, tot);
    } else {
        // ------- BTL path: 16 CONTIGUOUS upper-tri pairs per block -------
        int q = (blockIdx.x - AR_BLOCKS) * PAIRS_PER_BLK;
        // triu pair index -> (i, j): offset(i) = i*(511-i)/2  (once per block)
        int i = (int)((511.0 - sqrt((double)(261121 - 8 * q))) * 0.5);
        if (i < 0) i = 0;
        if (i > 254) i = 254;
        while (i < 254 && ((i + 1) * (511 - (i + 1))) / 2 <= q) ++i;
        while ((i * (511 - i)) / 2 > q) --i;
        int j = q - (i * (511 - i)) / 2 + i + 1;

        const int toff = tid * 4;
        f4 si = *(const f4*)(alpha + (size_t)i * ALPHA_LD + P_AR + toff);

        float acc = 0.f;
        for (int p = 0; p < PAIRS_PER_BLK; ++p) {
            const size_t base = ((size_t)i * N_P + j) * T_T + toff;
            const f4 z  = __builtin_nontemporal_load((const f4*)(Z + base));
            const f4 w  = __builtin_nontemporal_load((const f4*)(W + base));
            const f4 sj = *(const f4*)(alpha + (size_t)j * ALPHA_LD + P_AR + toff);

            acc += btl_term(z.x, w.x, si.x, sj.x);
            acc += btl_term(z.y, w.y, si.y, sj.y);
            acc += btl_term(z.z, w.z, si.z, sj.z);
            acc += btl_term(z.w, w.w, si.w, sj.w);

            // advance to next contiguous pair (uniform branch, rarely taken)
            if (++j == N_P) {
                ++i;
                j = i + 1;
                si = *(const f4*)(alpha + (size_t)i * ALPHA_LD + P_AR + toff);
            }
        }
        float tot = block_reduce_sum(acc, tmp);
        if (tid == 0) atomicAdd(out, tot);
    }
}

extern "C" void kernel_launch(void* const* d_in, const int* in_sizes, int n_in,
                              void* d_out, int out_size, void* d_ws, size_t ws_size,
                              hipStream_t stream) {
    const float* Z     = (const float*)d_in[0];
    const float* W     = (const float*)d_in[1];
    const float* Phi   = (const float*)d_in[2];
    const float* alpha = (const float*)d_in[3];
    float* out = (float*)d_out;

    hipMemsetAsync(d_out, 0, 2 * sizeof(float), stream);
    hipLaunchKernelGGL(fused_kernel, dim3(AR_BLOCKS + BTL_BLOCKS), dim3(256), 0, stream,
                       Z, W, Phi, alpha, out);
}